// Round 9
// baseline (249.342 us; speedup 1.0000x reference)
//
#include <hip/hip_runtime.h>
#include <hip/hip_bf16.h>

#define NT 4096      // H*W
#define CF 256       // feature channels
// CQK = 64

typedef __attribute__((ext_vector_type(8))) short bf16x8;
typedef __attribute__((ext_vector_type(4))) float f32x4;
typedef __attribute__((ext_vector_type(4))) short s16x4;

__device__ __forceinline__ short f2bf(float f) {
  union { float f; unsigned u; } v; v.f = f;
  unsigned r = v.u + 0x7FFFu + ((v.u >> 16) & 1u);   // RTNE
  return (short)(r >> 16);
}

// async global->LDS, 16B per lane; LDS dest = wave-uniform base + lane*16
__device__ __forceinline__ void glds16(const void* g, void* l) {
  __builtin_amdgcn_global_load_lds(
      (const __attribute__((address_space(1))) void*)g,
      (__attribute__((address_space(3))) void*)l, 16, 0, 0);
}

// bare hardware exp2 (log2-domain scores shifted to <= ~0; finite args)
__device__ __forceinline__ float fexp2(float x) {
  float r;
  asm("v_exp_f32 %0, %1" : "=v"(r) : "v"(x));
  return r;
}

// ---------------------------------------------------------------------------
// Projection: Y[i,o] = (sum_c X[c,i] * W[o,c] + bias[o]) * scale, bf16 output.
// TRANS=false -> Y (B,NT,O) row-major;  TRANS=true -> Y (B,O,NT).
// ---------------------------------------------------------------------------
template<int O, bool TRANS>
__global__ __launch_bounds__(256, 2)
void proj_kernel(const float* __restrict__ X, const float* __restrict__ W,
                 const float* __restrict__ Bv, short* __restrict__ Y, float scale)
{
  __shared__ alignas(16) short Xlds[64 * 256];   // [i][c] bf16, XOR-swizzled
  const int tid = threadIdx.x;
  const int wv = tid >> 6, l = tid & 63;
  const int l15 = l & 15, l4 = l >> 4;
  const int i0 = blockIdx.x * 64;
  const int b  = blockIdx.y;
  const float* Xb = X + (size_t)b * CF * NT;

#pragma unroll
  for (int it = 0; it < 16; ++it) {
    int c0 = it * 16 + wv * 4;
    float x0 = Xb[(size_t)(c0 + 0) * NT + i0 + l];
    float x1 = Xb[(size_t)(c0 + 1) * NT + i0 + l];
    float x2 = Xb[(size_t)(c0 + 2) * NT + i0 + l];
    float x3 = Xb[(size_t)(c0 + 3) * NT + i0 + l];
    s16x4 pk; pk[0] = f2bf(x0); pk[1] = f2bf(x1); pk[2] = f2bf(x2); pk[3] = f2bf(x3);
    int phys = (l * 512 + c0 * 2) ^ ((l & 31) << 4);
    *(s16x4*)((char*)Xlds + phys) = pk;
  }
  __syncthreads();

  constexpr int NO = O / 64;
  f32x4 acc[4][NO] = {};

#pragma unroll
  for (int kk = 0; kk < 8; ++kk) {
    bf16x8 a[4];
#pragma unroll
    for (int mi = 0; mi < 4; ++mi) {
      int i = 16 * mi + l15;
      int phys = (i * 512 + kk * 64 + l4 * 16) ^ ((i & 31) << 4);
      a[mi] = *(const bf16x8*)((const char*)Xlds + phys);
    }
#pragma unroll
    for (int no = 0; no < NO; ++no) {
      int o = wv * (O / 4) + 16 * no + l15;
      const float* wp = W + (size_t)o * CF + kk * 32 + l4 * 8;
      bf16x8 wf;
#pragma unroll
      for (int t = 0; t < 8; ++t) wf[t] = f2bf(wp[t]);
#pragma unroll
      for (int mi = 0; mi < 4; ++mi)
        acc[mi][no] = __builtin_amdgcn_mfma_f32_16x16x32_bf16(a[mi], wf, acc[mi][no], 0, 0, 0);
    }
  }

#pragma unroll
  for (int no = 0; no < NO; ++no) {
    int o = wv * (O / 4) + 16 * no + l15;
    float bv = Bv[o];
#pragma unroll
    for (int mi = 0; mi < 4; ++mi) {
      if (TRANS) {
        s16x4 pk;
#pragma unroll
        for (int r = 0; r < 4; ++r) pk[r] = f2bf((acc[mi][no][r] + bv) * scale);
        *(s16x4*)&Y[((size_t)b * O + o) * NT + i0 + 16 * mi + l4 * 4] = pk;
      } else {
#pragma unroll
        for (int r = 0; r < 4; ++r) {
          int i = i0 + 16 * mi + l4 * 4 + r;
          Y[((size_t)b * NT + i) * O + o] = f2bf((acc[mi][no][r] + bv) * scale);
        }
      }
    }
  }
}

// ---------------------------------------------------------------------------
// Static softmax bound precompute (Cauchy-Schwarz shift; see R8 notes).
// ---------------------------------------------------------------------------
__global__ void zero_kmax_kernel(unsigned* kmax) {
  if (threadIdx.x < 4) kmax[threadIdx.x] = 0u;
}

__global__ void norm_kernel(const short* __restrict__ Q, const short* __restrict__ K,
                            float* __restrict__ qnorm, unsigned* __restrict__ kmax)
{
  const int row = blockIdx.x * 256 + threadIdx.x;
  const int b = blockIdx.y;
  const short* P = (blockIdx.z ? K : Q) + ((size_t)b * NT + row) * 64;
  float ss = 0.f;
#pragma unroll
  for (int t = 0; t < 8; ++t) {
    bf16x8 v = *(const bf16x8*)&P[t * 8];
#pragma unroll
    for (int e = 0; e < 8; ++e) {
      union { unsigned u; float f; } w; w.u = ((unsigned)(unsigned short)v[e]) << 16;
      ss += w.f * w.f;
    }
  }
  float n = sqrtf(ss);
  if (blockIdx.z == 0) qnorm[(size_t)b * NT + row] = n;
  else atomicMax(&kmax[b], __float_as_uint(n));
}

// ---------------------------------------------------------------------------
// Flash attention + residual.  LDS-staged K/V, TRIPLE-buffered, with
// next-tile fragment prefetch into registers (2-state fA/fB, unroll-2 loop).
// Q (B,NT,64) bf16 pre-scaled by (1/16)*log2(e), K (B,NT,64), Vt (B,256,NT).
// wg = 4 waves (2x2) = 64 q-rows x 128 cols; wave = 32 q-rows x 64 cols.
// STATIC softmax shift M_i = qnorm_i*kmax folded into QK C-init; no max,
// no cross-lane reduce, no branch in the loop (sums reduced in epilogue).
// Arena: K bufs 3x8KB at 0; V bufs 3x16KB at 24576; 72KB -> 2 wg/CU.
// ---------------------------------------------------------------------------
struct Frags { bf16x8 kf[4][2]; bf16x8 vb[4][2]; };

__global__ __launch_bounds__(256, 2)
void flash_kernel(const short* __restrict__ Q, const short* __restrict__ K,
                  const short* __restrict__ Vt, const float* __restrict__ src,
                  const float* __restrict__ gamma_p,
                  const float* __restrict__ qnorm, const unsigned* __restrict__ kmax,
                  float* __restrict__ out)
{
  __shared__ alignas(16) char arena[73728];

  const int tid = threadIdx.x;
  const int wv = tid >> 6, l = tid & 63;
  const int l15 = l & 15, l4 = l >> 4;

  // id -> (b, qt, z); batch pinned to an XCD pair for L2 locality
  const int id = blockIdx.x;
  const int x8 = id & 7;
  const int b  = x8 >> 1;
  const int widx = ((id >> 3) << 1) | (x8 & 1);   // 0..127
  const int qt = widx >> 1, z = widx & 1;
  const int i0 = qt * 64;
  const int cbase = z * 128;
  const int wr = wv >> 1, wc = wv & 1;
  const int rowbase = i0 + wr * 32;               // wave's 32 query rows
  const int colwave = wc * 64;                    // within wg's 128-col V tile

  const short* Qb = Q + (size_t)b * NT * 64;
  const char*  Kb = (const char*)(K  + (size_t)b * NT * 64);
  const char*  Vb = (const char*)(Vt + (size_t)b * CF * NT);

  // Q fragments: 2 groups of 16 rows (B-operand: col=l15, k=l4*8..)
  bf16x8 qf[2][2];
#pragma unroll
  for (int g = 0; g < 2; ++g)
#pragma unroll
    for (int kk = 0; kk < 2; ++kk)
      qf[g][kk] = *(const bf16x8*)&Qb[(size_t)(rowbase + 16 * g + l15) * 64 + kk * 32 + l4 * 8];

  // static shift: C-init for QK = -M_i (per-lane row l15 of each group)
  const float kmx = __uint_as_float(kmax[b]);
  f32x4 c0[2];
#pragma unroll
  for (int g = 0; g < 2; ++g) {
    float mneg = -(qnorm[(size_t)b * NT + rowbase + 16 * g + l15] * kmx);
    c0[g][0] = mneg; c0[g][1] = mneg; c0[g][2] = mneg; c0[g][3] = mneg;
  }

  const int a32 = ((l ^ 32) << 2);                // bpermute byte index (epilogue)

  // reader per-lane byte offsets within one K/V buffer (loop-invariant)
  const int kperm = 8 * (l15 >> 2) + (l15 & 3);
  const int swzk = (l15 & 3) | (((l15 >> 2) & 1) << 2);
  const int swzv = (l15 & 3) | (((l15 >> 3) & 1) << 2);
  int baseK[2], baseV[2];
#pragma unroll
  for (int kk = 0; kk < 2; ++kk) {
    baseK[kk] = kperm * 128 + (((kk * 4 + l4) ^ swzk) << 4);
    baseV[kk] = (colwave + l15) * 128 + (((kk * 4 + l4) ^ swzv) << 4);
  }

  // staging: 24 1KB chunks/tile (K 8, V 16), 6 per wave; linear LDS dest +
  // inverse-swizzled global source (swz = (row&3) | ((row>>3&1)<<2))
  const char* sptr[6]; int sinc[6], dbase[6], dmul[6];
#pragma unroll
  for (int i = 0; i < 6; ++i) {
    int c = wv * 6 + i;
    if (c < 8) {              // K chunk: rows 8c..8c+7 (128B rows)
      int r = c * 8 + (l >> 3);
      int sw = (r & 3) | (((r >> 3) & 1) << 2);
      sptr[i] = Kb + r * 128 + (((l & 7) ^ sw) << 4);
      sinc[i] = 8192;         // next 64 keys
      dbase[i] = c * 1024;    // within K region (base 0)
      dmul[i] = 8192;
    } else {                  // V chunk: channels 8(c-8)..+7 of wg's 128
      int vr = (c - 8) * 8 + (l >> 3);
      int sw = (vr & 3) | (((vr >> 3) & 1) << 2);
      sptr[i] = Vb + (size_t)(cbase + vr) * (NT * 2) + (((l & 7) ^ sw) << 4);
      sinc[i] = 128;          // next 64 keys
      dbase[i] = 24576 + (c - 8) * 1024;   // within V region
      dmul[i] = 16384;
    }
  }

  // stage next pending tile into buffer bi (0..2); advances sptr
  auto stage_tile = [&](int bi) {
#pragma unroll
    for (int i = 0; i < 6; ++i) {
      glds16(sptr[i], arena + dbase[i] + bi * dmul[i]);
      sptr[i] += sinc[i];
    }
  };

  // load K/V fragments for a tile from buffer bi into F (registers)
  auto load_frags = [&](Frags& F, int bi) {
    const char* Kc = arena + bi * 8192;
    const char* Vc = arena + 24576 + bi * 16384;
#pragma unroll
    for (int nj = 0; nj < 4; ++nj) {
      const int ko = (nj >> 1) * 4096 + (nj & 1) * 512;
#pragma unroll
      for (int kk = 0; kk < 2; ++kk)
        F.kf[nj][kk] = *(const bf16x8*)(Kc + baseK[kk] + ko);
    }
#pragma unroll
    for (int nv = 0; nv < 4; ++nv)
#pragma unroll
      for (int kk = 0; kk < 2; ++kk)
        F.vb[nv][kk] = *(const bf16x8*)(Vc + baseV[kk] + nv * 2048);
  };

  f32x4 acc[2][4] = {};
  float lrow[2] = { 0.f, 0.f };   // per-lane PARTIAL sums (own 16 key-slots)

  // compute one tile entirely from register fragments
  auto compute_tile = [&](const Frags& F) {
    f32x4 s[2][4];
    __builtin_amdgcn_s_setprio(1);
#pragma unroll
    for (int nj = 0; nj < 4; ++nj)
#pragma unroll
      for (int g = 0; g < 2; ++g) {
        s[g][nj] = __builtin_amdgcn_mfma_f32_16x16x32_bf16(F.kf[nj][0], qf[g][0], c0[g], 0, 0, 0);
        s[g][nj] = __builtin_amdgcn_mfma_f32_16x16x32_bf16(F.kf[nj][1], qf[g][1], s[g][nj], 0, 0, 0);
      }
    __builtin_amdgcn_s_setprio(0);

    bf16x8 pa[2][2];
#pragma unroll
    for (int g = 0; g < 2; ++g) {
#pragma unroll
      for (int nj = 0; nj < 4; ++nj)
#pragma unroll
        for (int r = 0; r < 4; ++r)
          s[g][nj][r] = fexp2(s[g][nj][r]);

      lrow[g] += ((s[g][0][0] + s[g][0][1]) + (s[g][0][2] + s[g][0][3]))
               + ((s[g][1][0] + s[g][1][1]) + (s[g][1][2] + s[g][1][3]))
               + ((s[g][2][0] + s[g][2][1]) + (s[g][2][2] + s[g][2][3]))
               + ((s[g][3][0] + s[g][3][1]) + (s[g][3][2] + s[g][3][3]));

      unsigned pk[4][2];
#pragma unroll
      for (int nj = 0; nj < 4; ++nj)
#pragma unroll
        for (int h = 0; h < 2; ++h)
          asm("v_cvt_pk_bf16_f32 %0, %1, %2"
              : "=v"(pk[nj][h]) : "v"(s[g][nj][2 * h]), "v"(s[g][nj][2 * h + 1]));
#pragma unroll
      for (int kk = 0; kk < 2; ++kk) {
        union { unsigned u[4]; bf16x8 v; } u;
        u.u[0] = pk[2 * kk][0];     u.u[1] = pk[2 * kk][1];
        u.u[2] = pk[2 * kk + 1][0]; u.u[3] = pk[2 * kk + 1][1];
        pa[g][kk] = u.v;
      }
    }

    __builtin_amdgcn_s_setprio(1);
#pragma unroll
    for (int kk = 0; kk < 2; ++kk)
#pragma unroll
      for (int g = 0; g < 2; ++g)
#pragma unroll
        for (int nv = 0; nv < 4; ++nv)
          acc[g][nv] = __builtin_amdgcn_mfma_f32_16x16x32_bf16(pa[g][kk], F.vb[nv][kk], acc[g][nv], 0, 0, 0);
    __builtin_amdgcn_s_setprio(0);
  };

  // ---- prologue: tiles 0,1 staged; tile 0 fragments in registers ----
  Frags fA, fB;
  stage_tile(0);               // tile 0 -> buf 0
  __syncthreads();             // buf0 valid
  load_frags(fA, 0);           // tile 0 frags
  stage_tile(1);               // tile 1 -> buf 1
  __syncthreads();             // buf1 valid; fA complete (lgkmcnt 0)

  int st = 2, rd = 1;          // next stage buffer / next read buffer
  for (int jb = 0; jb < 64; jb += 2) {
    // even tile jb: compute fA, prefetch fB (tile jb+1)
    if (jb + 2 < 64) { stage_tile(st); st = (st == 2) ? 0 : st + 1; }
    load_frags(fB, rd); rd = (rd == 2) ? 0 : rd + 1;
    compute_tile(fA);
    __syncthreads();
    // odd tile jb+1: compute fB, prefetch fA (tile jb+2)
    if (jb + 3 < 64) { stage_tile(st); st = (st == 2) ? 0 : st + 1; }
    if (jb + 2 < 64) { load_frags(fA, rd); rd = (rd == 2) ? 0 : rd + 1; }
    compute_tile(fB);
    __syncthreads();
  }

  // ---- epilogue: reduce row sums ONCE, normalize, transpose, residual ----
  float* Obuf = (float*)(void*)arena + wv * (16 * 68);
  const float gm = gamma_p[0];
  const float* srcb = src + (size_t)b * CF * NT;
  float* outb = out + (size_t)b * CF * NT;

#pragma unroll
  for (int g = 0; g < 2; ++g) {
    float lf = lrow[g];
    lf += __int_as_float(__builtin_amdgcn_ds_swizzle(__float_as_int(lf), 0x401F));
    lf += __int_as_float(__builtin_amdgcn_ds_bpermute(a32, __float_as_int(lf)));
    float li[4];
#pragma unroll
    for (int r = 0; r < 4; ++r)
      li[r] = 1.0f / __shfl(lf, 4 * l4 + r, 64);
#pragma unroll
    for (int nv = 0; nv < 4; ++nv)
#pragma unroll
      for (int r = 0; r < 4; ++r)
        Obuf[(4 * l4 + r) * 68 + 16 * nv + l15] = acc[g][nv][r] * li[r];
    // same-wave LDS write->read; per-wave disjoint regions, no barrier needed
#pragma unroll 4
    for (int t = 0; t < 16; ++t) {
      int c = cbase + colwave + l4 + 4 * t;
      size_t off = (size_t)c * NT + rowbase + 16 * g + l15;
      float v = Obuf[l15 * 68 + l4 + 4 * t];
      outb[off] = gm * v + srcb[off];
    }
  }
}

// ---------------------------------------------------------------------------
extern "C" void kernel_launch(void* const* d_in, const int* in_sizes, int n_in,
                              void* d_out, int out_size, void* d_ws, size_t ws_size,
                              hipStream_t stream) {
  const float* src    = (const float*)d_in[0];
  const float* ref    = (const float*)d_in[1];
  const float* w_src  = (const float*)d_in[2];
  const float* b_src  = (const float*)d_in[3];
  const float* w_ref  = (const float*)d_in[4];
  const float* b_ref  = (const float*)d_in[5];
  const float* w_gate = (const float*)d_in[6];
  const float* b_gate = (const float*)d_in[7];
  const float* gamma  = (const float*)d_in[8];
  float* out = (float*)d_out;

  const size_t qk_elems = (size_t)4 * NT * 64;
  const size_t v_elems  = (size_t)4 * CF * NT;
  const size_t base_bytes = (qk_elems * 2 + v_elems) * sizeof(short);
  if (ws_size < base_bytes + 4 * NT * sizeof(float) + 4 * sizeof(unsigned)) return;
  short* Qw = (short*)d_ws;
  short* Kw = Qw + qk_elems;
  short* Vw = Kw + qk_elems;
  float* qnormp = (float*)(Vw + v_elems);
  unsigned* kmaxp = (unsigned*)(qnormp + 4 * NT);

  dim3 blk(256);
  dim3 gp(NT / 64, 4);
  zero_kmax_kernel<<<1, 64, 0, stream>>>(kmaxp);
  // fold energy scale (1/16) AND log2(e) into Q so scores are log2-domain
  proj_kernel<64,  false><<<gp, blk, 0, stream>>>(src, w_src,  b_src,  Qw, 0.0625f * 1.44269504f);
  proj_kernel<64,  false><<<gp, blk, 0, stream>>>(ref, w_ref,  b_ref,  Kw, 1.0f);
  proj_kernel<256, true ><<<gp, blk, 0, stream>>>(ref, w_gate, b_gate, Vw, 1.0f);
  norm_kernel<<<dim3(NT / 256, 4, 2), blk, 0, stream>>>(Qw, Kw, qnormp, kmaxp);

  flash_kernel<<<dim3(512), blk, 0, stream>>>(Qw, Kw, Vw, src, gamma, qnormp, kmaxp, out);
}

// Round 10
// 116.012 us; speedup vs baseline: 2.1493x; 2.1493x over previous
//
#include <hip/hip_runtime.h>
#include <hip/hip_bf16.h>

#define NT 4096      // H*W
#define CF 256       // feature channels
// CQK = 64

typedef __attribute__((ext_vector_type(8))) short bf16x8;
typedef __attribute__((ext_vector_type(4))) float f32x4;
typedef __attribute__((ext_vector_type(4))) short s16x4;

__device__ __forceinline__ short f2bf(float f) {
  union { float f; unsigned u; } v; v.f = f;
  unsigned r = v.u + 0x7FFFu + ((v.u >> 16) & 1u);   // RTNE
  return (short)(r >> 16);
}
__device__ __forceinline__ float bf2f(short s) {
  union { unsigned u; float f; } w; w.u = ((unsigned)(unsigned short)s) << 16;
  return w.f;
}

// async global->LDS, 16B per lane; LDS dest = wave-uniform base + lane*16
__device__ __forceinline__ void glds16(const void* g, void* l) {
  __builtin_amdgcn_global_load_lds(
      (const __attribute__((address_space(1))) void*)g,
      (__attribute__((address_space(3))) void*)l, 16, 0, 0);
}

// bare hardware exp2 (log2-domain scores shifted to <= ~0; finite args)
__device__ __forceinline__ float fexp2(float x) {
  float r;
  asm("v_exp_f32 %0, %1" : "=v"(r) : "v"(x));
  return r;
}

// ---------------------------------------------------------------------------
// Q projection + per-row squared norm (for the static softmax bound).
// Y (B,NT,64) bf16 = (src . w_src + b) * scale;  qnorm2[b][i] = sum_o y^2
// (computed on the ROUNDED bf16 values -- identical bound to the old
// separate norm kernel).
// ---------------------------------------------------------------------------
__global__ __launch_bounds__(256, 2)
void proj_src_kernel(const float* __restrict__ X, const float* __restrict__ W,
                     const float* __restrict__ Bv, short* __restrict__ Y,
                     float scale, float* __restrict__ qnorm2)
{
  __shared__ alignas(16) short Xlds[64 * 256];   // 32KB; reused as norm scratch
  const int tid = threadIdx.x;
  const int wv = tid >> 6, l = tid & 63;
  const int l15 = l & 15, l4 = l >> 4;
  const int i0 = blockIdx.x * 64;
  const int b  = blockIdx.y;
  const float* Xb = X + (size_t)b * CF * NT;

#pragma unroll
  for (int it = 0; it < 16; ++it) {
    int c0 = it * 16 + wv * 4;
    float x0 = Xb[(size_t)(c0 + 0) * NT + i0 + l];
    float x1 = Xb[(size_t)(c0 + 1) * NT + i0 + l];
    float x2 = Xb[(size_t)(c0 + 2) * NT + i0 + l];
    float x3 = Xb[(size_t)(c0 + 3) * NT + i0 + l];
    s16x4 pk; pk[0] = f2bf(x0); pk[1] = f2bf(x1); pk[2] = f2bf(x2); pk[3] = f2bf(x3);
    int phys = (l * 512 + c0 * 2) ^ ((l & 31) << 4);
    *(s16x4*)((char*)Xlds + phys) = pk;
  }
  __syncthreads();

  f32x4 acc[4] = {};
  const int o = wv * 16 + l15;

#pragma unroll
  for (int kk = 0; kk < 8; ++kk) {
    bf16x8 a[4];
#pragma unroll
    for (int mi = 0; mi < 4; ++mi) {
      int i = 16 * mi + l15;
      int phys = (i * 512 + kk * 64 + l4 * 16) ^ ((i & 31) << 4);
      a[mi] = *(const bf16x8*)((const char*)Xlds + phys);
    }
    const float* wp = W + (size_t)o * CF + kk * 32 + l4 * 8;
    bf16x8 wf;
#pragma unroll
    for (int t = 0; t < 8; ++t) wf[t] = f2bf(wp[t]);
#pragma unroll
    for (int mi = 0; mi < 4; ++mi)
      acc[mi] = __builtin_amdgcn_mfma_f32_16x16x32_bf16(a[mi], wf, acc[mi], 0, 0, 0);
  }

  __syncthreads();                         // all waves done reading Xlds
  float* nlds = (float*)(void*)Xlds;       // [64][65] padded sq matrix
  const float bv = Bv[o];
#pragma unroll
  for (int mi = 0; mi < 4; ++mi)
#pragma unroll
    for (int r = 0; r < 4; ++r) {
      float val = (acc[mi][r] + bv) * scale;
      short sv = f2bf(val);
      int row = 16 * mi + l4 * 4 + r;
      Y[((size_t)b * NT + i0 + row) * 64 + o] = sv;
      float qr = bf2f(sv);
      nlds[row * 65 + o] = qr * qr;
    }
  __syncthreads();
  if (tid < 64) {
    float ss = 0.f;
#pragma unroll 8
    for (int j = 0; j < 64; ++j) ss += nlds[tid * 65 + j];
    qnorm2[(size_t)b * NT + i0 + tid] = ss;
  }
}

// ---------------------------------------------------------------------------
// Fused ref projections: K (B,NT,64) and Vt (B,256,NT) from ONE staging of
// ref, plus kmax2[b] = max_row |k_row|^2 (one atomicMax per wg).
// ---------------------------------------------------------------------------
__global__ __launch_bounds__(256, 2)
void proj_ref_kernel(const float* __restrict__ X,
                     const float* __restrict__ Wk, const float* __restrict__ Bk,
                     const float* __restrict__ Wv, const float* __restrict__ Bvv,
                     short* __restrict__ K, short* __restrict__ Vt,
                     unsigned* __restrict__ kmax2)
{
  __shared__ alignas(16) short Xlds[64 * 256];
  const int tid = threadIdx.x;
  const int wv = tid >> 6, l = tid & 63;
  const int l15 = l & 15, l4 = l >> 4;
  const int i0 = blockIdx.x * 64;
  const int b  = blockIdx.y;
  const float* Xb = X + (size_t)b * CF * NT;

#pragma unroll
  for (int it = 0; it < 16; ++it) {
    int c0 = it * 16 + wv * 4;
    float x0 = Xb[(size_t)(c0 + 0) * NT + i0 + l];
    float x1 = Xb[(size_t)(c0 + 1) * NT + i0 + l];
    float x2 = Xb[(size_t)(c0 + 2) * NT + i0 + l];
    float x3 = Xb[(size_t)(c0 + 3) * NT + i0 + l];
    s16x4 pk; pk[0] = f2bf(x0); pk[1] = f2bf(x1); pk[2] = f2bf(x2); pk[3] = f2bf(x3);
    int phys = (l * 512 + c0 * 2) ^ ((l & 31) << 4);
    *(s16x4*)((char*)Xlds + phys) = pk;
  }
  __syncthreads();

  f32x4 accK[4] = {};
  f32x4 accV[4][4] = {};
  const int oK = wv * 16 + l15;

#pragma unroll
  for (int kk = 0; kk < 8; ++kk) {
    bf16x8 a[4];
#pragma unroll
    for (int mi = 0; mi < 4; ++mi) {
      int i = 16 * mi + l15;
      int phys = (i * 512 + kk * 64 + l4 * 16) ^ ((i & 31) << 4);
      a[mi] = *(const bf16x8*)((const char*)Xlds + phys);
    }
    // K part (O=64)
    {
      const float* wp = Wk + (size_t)oK * CF + kk * 32 + l4 * 8;
      bf16x8 wf;
#pragma unroll
      for (int t = 0; t < 8; ++t) wf[t] = f2bf(wp[t]);
#pragma unroll
      for (int mi = 0; mi < 4; ++mi)
        accK[mi] = __builtin_amdgcn_mfma_f32_16x16x32_bf16(a[mi], wf, accK[mi], 0, 0, 0);
    }
    // V part (O=256)
#pragma unroll
    for (int no = 0; no < 4; ++no) {
      int oV = wv * 64 + 16 * no + l15;
      const float* wp = Wv + (size_t)oV * CF + kk * 32 + l4 * 8;
      bf16x8 wf;
#pragma unroll
      for (int t = 0; t < 8; ++t) wf[t] = f2bf(wp[t]);
#pragma unroll
      for (int mi = 0; mi < 4; ++mi)
        accV[mi][no] = __builtin_amdgcn_mfma_f32_16x16x32_bf16(a[mi], wf, accV[mi][no], 0, 0, 0);
    }
  }

  // V epilogue (TRANS layout, packed 8B stores) -- does not touch Xlds
#pragma unroll
  for (int no = 0; no < 4; ++no) {
    int oV = wv * 64 + 16 * no + l15;
    float bv = Bvv[oV];
#pragma unroll
    for (int mi = 0; mi < 4; ++mi) {
      s16x4 pk;
#pragma unroll
      for (int r = 0; r < 4; ++r) pk[r] = f2bf(accV[mi][no][r] + bv);
      *(s16x4*)&Vt[((size_t)b * CF + oV) * NT + i0 + 16 * mi + l4 * 4] = pk;
    }
  }

  // K epilogue + squared-norm scratch
  __syncthreads();                         // all waves done reading Xlds
  float* nlds = (float*)(void*)Xlds;       // [64][65]
  const float bk = Bk[oK];
#pragma unroll
  for (int mi = 0; mi < 4; ++mi)
#pragma unroll
    for (int r = 0; r < 4; ++r) {
      float val = accK[mi][r] + bk;
      short sv = f2bf(val);
      int row = 16 * mi + l4 * 4 + r;
      K[((size_t)b * NT + i0 + row) * 64 + oK] = sv;
      float qr = bf2f(sv);
      nlds[row * 65 + oK] = qr * qr;
    }
  __syncthreads();
  if (tid < 64) {
    float ss = 0.f;
#pragma unroll 8
    for (int j = 0; j < 64; ++j) ss += nlds[tid * 65 + j];
    // wave-wide max, one atomic per wg
#pragma unroll
    for (int m = 1; m <= 32; m <<= 1) ss = fmaxf(ss, __shfl_xor(ss, m, 64));
    if (tid == 0) atomicMax(&kmax2[b], __float_as_uint(ss));
  }
}

// ---------------------------------------------------------------------------
// Flash attention + residual.  LDS-staged K/V (global_load_lds, dbuf).
// EXACT R8 structure (90us proven); only change: qnorm/kmax are SQUARED,
// one sqrtf at c0 setup.
// ---------------------------------------------------------------------------
__global__ __launch_bounds__(256, 2)
void flash_kernel(const short* __restrict__ Q, const short* __restrict__ K,
                  const short* __restrict__ Vt, const float* __restrict__ src,
                  const float* __restrict__ gamma_p,
                  const float* __restrict__ qnorm2, const unsigned* __restrict__ kmax2,
                  float* __restrict__ out)
{
  // arena: K dbuf 2x8KB at 0; V dbuf 2x16KB at 16384; epilogue reuse.
  __shared__ alignas(16) char arena[49152];

  const int tid = threadIdx.x;
  const int wv = tid >> 6, l = tid & 63;
  const int l15 = l & 15, l4 = l >> 4;

  // id -> (b, qt, z); batch pinned to an XCD pair for L2 locality
  const int id = blockIdx.x;
  const int x8 = id & 7;
  const int b  = x8 >> 1;
  const int widx = ((id >> 3) << 1) | (x8 & 1);   // 0..127
  const int qt = widx >> 1, z = widx & 1;
  const int i0 = qt * 64;
  const int cbase = z * 128;
  const int wr = wv >> 1, wc = wv & 1;
  const int rowbase = i0 + wr * 32;               // wave's 32 query rows
  const int colwave = wc * 64;                    // within wg's 128-col V tile

  const short* Qb = Q + (size_t)b * NT * 64;
  const char*  Kb = (const char*)(K  + (size_t)b * NT * 64);
  const char*  Vb = (const char*)(Vt + (size_t)b * CF * NT);

  // Q fragments: 2 groups of 16 rows (B-operand: col=l15, k=l4*8..)
  bf16x8 qf[2][2];
#pragma unroll
  for (int g = 0; g < 2; ++g)
#pragma unroll
    for (int kk = 0; kk < 2; ++kk)
      qf[g][kk] = *(const bf16x8*)&Qb[(size_t)(rowbase + 16 * g + l15) * 64 + kk * 32 + l4 * 8];

  // static shift: C-init for QK = -M_i = -sqrt(qnorm2_i * kmax2)
  const float km2 = __uint_as_float(kmax2[b]);
  f32x4 c0[2];
#pragma unroll
  for (int g = 0; g < 2; ++g) {
    float mneg = -sqrtf(qnorm2[(size_t)b * NT + rowbase + 16 * g + l15] * km2);
    c0[g][0] = mneg; c0[g][1] = mneg; c0[g][2] = mneg; c0[g][3] = mneg;
  }

  const int a32 = ((l ^ 32) << 2);                // bpermute byte index (epilogue)

  // reader per-lane byte offsets (loop-invariant)
  const int kperm = 8 * (l15 >> 2) + (l15 & 3);
  const int swzk = (l15 & 3) | (((l15 >> 2) & 1) << 2);
  const int swzv = (l15 & 3) | (((l15 >> 3) & 1) << 2);
  int baseK[2], baseV[2];
#pragma unroll
  for (int kk = 0; kk < 2; ++kk) {
    baseK[kk] = kperm * 128 + (((kk * 4 + l4) ^ swzk) << 4);
    baseV[kk] = (colwave + l15) * 128 + (((kk * 4 + l4) ^ swzv) << 4);
  }

  // staging: 24 1KB chunks/tile (K 8, V 16), 6 per wave; linear LDS dest +
  // inverse-swizzled global source (swz = (row&3) | ((row>>3&1)<<2))
  const char* sptr[6]; int sinc[6], doff0[6], dadd[6];
#pragma unroll
  for (int i = 0; i < 6; ++i) {
    int c = wv * 6 + i;
    if (c < 8) {              // K chunk: rows 8c..8c+7 (128B rows)
      int r = c * 8 + (l >> 3);
      int sw = (r & 3) | (((r >> 3) & 1) << 2);
      sptr[i] = Kb + r * 128 + (((l & 7) ^ sw) << 4);
      sinc[i] = 8192;         // next 64 keys
      doff0[i] = c * 1024;
      dadd[i] = 8192;
    } else {                  // V chunk: channels 8(c-8)..+7 of wg's 128
      int vr = (c - 8) * 8 + (l >> 3);
      int sw = (vr & 3) | (((vr >> 3) & 1) << 2);
      sptr[i] = Vb + (size_t)(cbase + vr) * (NT * 2) + (((l & 7) ^ sw) << 4);
      sinc[i] = 128;          // next 64 keys
      doff0[i] = 16384 + (c - 8) * 1024;
      dadd[i] = 16384;
    }
  }

  // prologue: stage tile 0 into parity 0
#pragma unroll
  for (int i = 0; i < 6; ++i) {
    glds16(sptr[i], arena + doff0[i]);
    sptr[i] += sinc[i];
  }
  __syncthreads();

  f32x4 acc[2][4] = {};
  float lrow[2] = { 0.f, 0.f };   // per-lane PARTIAL sums (own 16 key-slots)

  for (int jb = 0; jb < 64; ++jb) {
    const int cur = jb & 1;
    const char* Kc = arena + cur * 8192;
    const char* Vc = arena + 16384 + cur * 16384;

    // stage next tile (async; has the whole compute phase to land)
    if (jb < 63) {
      const int p = cur ^ 1;
#pragma unroll
      for (int i = 0; i < 6; ++i) {
        glds16(sptr[i], arena + doff0[i] + p * dadd[i]);
        sptr[i] += sinc[i];
      }
    }

    // K fragments (A-operand, permuted rows), shared by both q-groups
    bf16x8 kf[4][2];
#pragma unroll
    for (int nj = 0; nj < 4; ++nj) {
      const int ko = (nj >> 1) * 4096 + (nj & 1) * 512;
#pragma unroll
      for (int kk = 0; kk < 2; ++kk)
        kf[nj][kk] = *(const bf16x8*)(Kc + baseK[kk] + ko);
    }

    // S^T = K_perm @ Q^T - M  (static shift folded into C-init)
    f32x4 s[2][4];
    __builtin_amdgcn_s_setprio(1);
#pragma unroll
    for (int nj = 0; nj < 4; ++nj)
#pragma unroll
      for (int g = 0; g < 2; ++g) {
        s[g][nj] = __builtin_amdgcn_mfma_f32_16x16x32_bf16(kf[nj][0], qf[g][0], c0[g], 0, 0, 0);
        s[g][nj] = __builtin_amdgcn_mfma_f32_16x16x32_bf16(kf[nj][1], qf[g][1], s[g][nj], 0, 0, 0);
      }
    __builtin_amdgcn_s_setprio(0);

    // V fragments (B-operand), shared by both q-groups
    bf16x8 vb[4][2];
#pragma unroll
    for (int nv = 0; nv < 4; ++nv)
#pragma unroll
      for (int kk = 0; kk < 2; ++kk)
        vb[nv][kk] = *(const bf16x8*)(Vc + baseV[kk] + nv * 2048);

    // softmax numerators: p = 2^s (s <= ~0 by the static bound); no reduce,
    // no branch.  Per-lane partial sum accumulates into lrow.
    bf16x8 pa[2][2];
#pragma unroll
    for (int g = 0; g < 2; ++g) {
#pragma unroll
      for (int nj = 0; nj < 4; ++nj)
#pragma unroll
        for (int r = 0; r < 4; ++r)
          s[g][nj][r] = fexp2(s[g][nj][r]);

      lrow[g] += ((s[g][0][0] + s[g][0][1]) + (s[g][0][2] + s[g][0][3]))
               + ((s[g][1][0] + s[g][1][1]) + (s[g][1][2] + s[g][1][3]))
               + ((s[g][2][0] + s[g][2][1]) + (s[g][2][2] + s[g][2][3]))
               + ((s[g][3][0] + s[g][3][1]) + (s[g][3][2] + s[g][3][3]));

      unsigned pk[4][2];
#pragma unroll
      for (int nj = 0; nj < 4; ++nj)
#pragma unroll
        for (int h = 0; h < 2; ++h)
          asm("v_cvt_pk_bf16_f32 %0, %1, %2"
              : "=v"(pk[nj][h]) : "v"(s[g][nj][2 * h]), "v"(s[g][nj][2 * h + 1]));
#pragma unroll
      for (int kk = 0; kk < 2; ++kk) {
        union { unsigned u[4]; bf16x8 v; } u;
        u.u[0] = pk[2 * kk][0];     u.u[1] = pk[2 * kk][1];
        u.u[2] = pk[2 * kk + 1][0]; u.u[3] = pk[2 * kk + 1][1];
        pa[g][kk] = u.v;
      }
    }

    // O += P @ V
    __builtin_amdgcn_s_setprio(1);
#pragma unroll
    for (int kk = 0; kk < 2; ++kk)
#pragma unroll
      for (int g = 0; g < 2; ++g)
#pragma unroll
        for (int nv = 0; nv < 4; ++nv)
          acc[g][nv] = __builtin_amdgcn_mfma_f32_16x16x32_bf16(pa[g][kk], vb[nv][kk], acc[g][nv], 0, 0, 0);
    __builtin_amdgcn_s_setprio(0);

    __syncthreads();   // implicit vmcnt(0): next-tile stage landed; reads done
  }

  // ---- epilogue: reduce row sums ONCE, normalize, transpose, residual ----
  float* Obuf = (float*)(void*)arena + wv * (16 * 68);
  const float gm = gamma_p[0];
  const float* srcb = src + (size_t)b * CF * NT;
  float* outb = out + (size_t)b * CF * NT;

#pragma unroll
  for (int g = 0; g < 2; ++g) {
    float lf = lrow[g];
    lf += __int_as_float(__builtin_amdgcn_ds_swizzle(__float_as_int(lf), 0x401F));
    lf += __int_as_float(__builtin_amdgcn_ds_bpermute(a32, __float_as_int(lf)));
    float li[4];
#pragma unroll
    for (int r = 0; r < 4; ++r)
      li[r] = 1.0f / __shfl(lf, 4 * l4 + r, 64);
#pragma unroll
    for (int nv = 0; nv < 4; ++nv)
#pragma unroll
      for (int r = 0; r < 4; ++r)
        Obuf[(4 * l4 + r) * 68 + 16 * nv + l15] = acc[g][nv][r] * li[r];
    // same-wave LDS write->read; per-wave disjoint regions, no barrier needed
#pragma unroll 4
    for (int t = 0; t < 16; ++t) {
      int c = cbase + colwave + l4 + 4 * t;
      size_t off = (size_t)c * NT + rowbase + 16 * g + l15;
      float v = Obuf[l15 * 68 + l4 + 4 * t];
      outb[off] = gm * v + srcb[off];
    }
  }
}

// ---------------------------------------------------------------------------
extern "C" void kernel_launch(void* const* d_in, const int* in_sizes, int n_in,
                              void* d_out, int out_size, void* d_ws, size_t ws_size,
                              hipStream_t stream) {
  const float* src    = (const float*)d_in[0];
  const float* ref    = (const float*)d_in[1];
  const float* w_src  = (const float*)d_in[2];
  const float* b_src  = (const float*)d_in[3];
  const float* w_ref  = (const float*)d_in[4];
  const float* b_ref  = (const float*)d_in[5];
  const float* w_gate = (const float*)d_in[6];
  const float* b_gate = (const float*)d_in[7];
  const float* gamma  = (const float*)d_in[8];
  float* out = (float*)d_out;

  const size_t qk_elems = (size_t)4 * NT * 64;
  const size_t v_elems  = (size_t)4 * CF * NT;
  const size_t base_bytes = (qk_elems * 2 + v_elems) * sizeof(short);
  if (ws_size < base_bytes + 4 * NT * sizeof(float) + 4 * sizeof(unsigned)) return;
  short* Qw = (short*)d_ws;
  short* Kw = Qw + qk_elems;
  short* Vw = Kw + qk_elems;
  float* qnormp = (float*)(Vw + v_elems);
  unsigned* kmaxp = (unsigned*)(qnormp + 4 * NT);

  hipMemsetAsync(kmaxp, 0, 4 * sizeof(unsigned), stream);

  dim3 blk(256);
  dim3 gp(NT / 64, 4);
  // fold energy scale (1/16) AND log2(e) into Q so scores are log2-domain
  proj_src_kernel<<<gp, blk, 0, stream>>>(src, w_src, b_src, Qw,
                                          0.0625f * 1.44269504f, qnormp);
  proj_ref_kernel<<<gp, blk, 0, stream>>>(ref, w_ref, b_ref, w_gate, b_gate,
                                          Kw, Vw, kmaxp);

  flash_kernel<<<dim3(512), blk, 0, stream>>>(Qw, Kw, Vw, src, gamma, qnormp, kmaxp, out);
}

// Round 11
// 102.305 us; speedup vs baseline: 2.4372x; 1.1340x over previous
//
#include <hip/hip_runtime.h>
#include <hip/hip_bf16.h>

#define NT 4096      // H*W
#define CF 256       // feature channels
// CQK = 64

typedef __attribute__((ext_vector_type(8))) short bf16x8;
typedef __attribute__((ext_vector_type(4))) float f32x4;
typedef __attribute__((ext_vector_type(4))) short s16x4;

__device__ __forceinline__ short f2bf(float f) {
  union { float f; unsigned u; } v; v.f = f;
  unsigned r = v.u + 0x7FFFu + ((v.u >> 16) & 1u);   // RTNE
  return (short)(r >> 16);
}
__device__ __forceinline__ float bf2f(short s) {
  union { unsigned u; float f; } w; w.u = ((unsigned)(unsigned short)s) << 16;
  return w.f;
}

// async global->LDS, 16B per lane; LDS dest = wave-uniform base + lane*16
__device__ __forceinline__ void glds16(const void* g, void* l) {
  __builtin_amdgcn_global_load_lds(
      (const __attribute__((address_space(1))) void*)g,
      (__attribute__((address_space(3))) void*)l, 16, 0, 0);
}

// bare hardware exp2 (log2-domain scores shifted to <= ~0; finite args)
__device__ __forceinline__ float fexp2(float x) {
  float r;
  asm("v_exp_f32 %0, %1" : "=v"(r) : "v"(x));
  return r;
}

// ---------------------------------------------------------------------------
// Q projection + per-row squared norm (for the static softmax bound).
// ---------------------------------------------------------------------------
__global__ __launch_bounds__(256, 2)
void proj_src_kernel(const float* __restrict__ X, const float* __restrict__ W,
                     const float* __restrict__ Bv, short* __restrict__ Y,
                     float scale, float* __restrict__ qnorm2)
{
  __shared__ alignas(16) short Xlds[64 * 256];   // 32KB; reused as norm scratch
  const int tid = threadIdx.x;
  const int wv = tid >> 6, l = tid & 63;
  const int l15 = l & 15, l4 = l >> 4;
  const int i0 = blockIdx.x * 64;
  const int b  = blockIdx.y;
  const float* Xb = X + (size_t)b * CF * NT;

#pragma unroll
  for (int it = 0; it < 16; ++it) {
    int c0 = it * 16 + wv * 4;
    float x0 = Xb[(size_t)(c0 + 0) * NT + i0 + l];
    float x1 = Xb[(size_t)(c0 + 1) * NT + i0 + l];
    float x2 = Xb[(size_t)(c0 + 2) * NT + i0 + l];
    float x3 = Xb[(size_t)(c0 + 3) * NT + i0 + l];
    s16x4 pk; pk[0] = f2bf(x0); pk[1] = f2bf(x1); pk[2] = f2bf(x2); pk[3] = f2bf(x3);
    int phys = (l * 512 + c0 * 2) ^ ((l & 31) << 4);
    *(s16x4*)((char*)Xlds + phys) = pk;
  }
  __syncthreads();

  f32x4 acc[4] = {};
  const int o = wv * 16 + l15;

#pragma unroll
  for (int kk = 0; kk < 8; ++kk) {
    bf16x8 a[4];
#pragma unroll
    for (int mi = 0; mi < 4; ++mi) {
      int i = 16 * mi + l15;
      int phys = (i * 512 + kk * 64 + l4 * 16) ^ ((i & 31) << 4);
      a[mi] = *(const bf16x8*)((const char*)Xlds + phys);
    }
    const float* wp = W + (size_t)o * CF + kk * 32 + l4 * 8;
    bf16x8 wf;
#pragma unroll
    for (int t = 0; t < 8; ++t) wf[t] = f2bf(wp[t]);
#pragma unroll
    for (int mi = 0; mi < 4; ++mi)
      acc[mi] = __builtin_amdgcn_mfma_f32_16x16x32_bf16(a[mi], wf, acc[mi], 0, 0, 0);
  }

  __syncthreads();                         // all waves done reading Xlds
  float* nlds = (float*)(void*)Xlds;       // [64][65] padded sq matrix
  const float bv = Bv[o];
#pragma unroll
  for (int mi = 0; mi < 4; ++mi)
#pragma unroll
    for (int r = 0; r < 4; ++r) {
      float val = (acc[mi][r] + bv) * scale;
      short sv = f2bf(val);
      int row = 16 * mi + l4 * 4 + r;
      Y[((size_t)b * NT + i0 + row) * 64 + o] = sv;
      float qr = bf2f(sv);
      nlds[row * 65 + o] = qr * qr;
    }
  __syncthreads();
  if (tid < 64) {
    float ss = 0.f;
#pragma unroll 8
    for (int j = 0; j < 64; ++j) ss += nlds[tid * 65 + j];
    qnorm2[(size_t)b * NT + i0 + tid] = ss;
  }
}

// ---------------------------------------------------------------------------
// Fused ref projections: K (B,NT,64) and Vt (B,256,NT) from ONE staging of
// ref, plus kmax2[b] = max_row |k_row|^2 (one atomicMax per wg).
// ---------------------------------------------------------------------------
__global__ __launch_bounds__(256, 2)
void proj_ref_kernel(const float* __restrict__ X,
                     const float* __restrict__ Wk, const float* __restrict__ Bk,
                     const float* __restrict__ Wv, const float* __restrict__ Bvv,
                     short* __restrict__ K, short* __restrict__ Vt,
                     unsigned* __restrict__ kmax2)
{
  __shared__ alignas(16) short Xlds[64 * 256];
  const int tid = threadIdx.x;
  const int wv = tid >> 6, l = tid & 63;
  const int l15 = l & 15, l4 = l >> 4;
  const int i0 = blockIdx.x * 64;
  const int b  = blockIdx.y;
  const float* Xb = X + (size_t)b * CF * NT;

#pragma unroll
  for (int it = 0; it < 16; ++it) {
    int c0 = it * 16 + wv * 4;
    float x0 = Xb[(size_t)(c0 + 0) * NT + i0 + l];
    float x1 = Xb[(size_t)(c0 + 1) * NT + i0 + l];
    float x2 = Xb[(size_t)(c0 + 2) * NT + i0 + l];
    float x3 = Xb[(size_t)(c0 + 3) * NT + i0 + l];
    s16x4 pk; pk[0] = f2bf(x0); pk[1] = f2bf(x1); pk[2] = f2bf(x2); pk[3] = f2bf(x3);
    int phys = (l * 512 + c0 * 2) ^ ((l & 31) << 4);
    *(s16x4*)((char*)Xlds + phys) = pk;
  }
  __syncthreads();

  f32x4 accK[4] = {};
  f32x4 accV[4][4] = {};
  const int oK = wv * 16 + l15;

#pragma unroll
  for (int kk = 0; kk < 8; ++kk) {
    bf16x8 a[4];
#pragma unroll
    for (int mi = 0; mi < 4; ++mi) {
      int i = 16 * mi + l15;
      int phys = (i * 512 + kk * 64 + l4 * 16) ^ ((i & 31) << 4);
      a[mi] = *(const bf16x8*)((const char*)Xlds + phys);
    }
    {
      const float* wp = Wk + (size_t)oK * CF + kk * 32 + l4 * 8;
      bf16x8 wf;
#pragma unroll
      for (int t = 0; t < 8; ++t) wf[t] = f2bf(wp[t]);
#pragma unroll
      for (int mi = 0; mi < 4; ++mi)
        accK[mi] = __builtin_amdgcn_mfma_f32_16x16x32_bf16(a[mi], wf, accK[mi], 0, 0, 0);
    }
#pragma unroll
    for (int no = 0; no < 4; ++no) {
      int oV = wv * 64 + 16 * no + l15;
      const float* wp = Wv + (size_t)oV * CF + kk * 32 + l4 * 8;
      bf16x8 wf;
#pragma unroll
      for (int t = 0; t < 8; ++t) wf[t] = f2bf(wp[t]);
#pragma unroll
      for (int mi = 0; mi < 4; ++mi)
        accV[mi][no] = __builtin_amdgcn_mfma_f32_16x16x32_bf16(a[mi], wf, accV[mi][no], 0, 0, 0);
    }
  }

#pragma unroll
  for (int no = 0; no < 4; ++no) {
    int oV = wv * 64 + 16 * no + l15;
    float bv = Bvv[oV];
#pragma unroll
    for (int mi = 0; mi < 4; ++mi) {
      s16x4 pk;
#pragma unroll
      for (int r = 0; r < 4; ++r) pk[r] = f2bf(accV[mi][no][r] + bv);
      *(s16x4*)&Vt[((size_t)b * CF + oV) * NT + i0 + 16 * mi + l4 * 4] = pk;
    }
  }

  __syncthreads();                         // all waves done reading Xlds
  float* nlds = (float*)(void*)Xlds;       // [64][65]
  const float bk = Bk[oK];
#pragma unroll
  for (int mi = 0; mi < 4; ++mi)
#pragma unroll
    for (int r = 0; r < 4; ++r) {
      float val = accK[mi][r] + bk;
      short sv = f2bf(val);
      int row = 16 * mi + l4 * 4 + r;
      K[((size_t)b * NT + i0 + row) * 64 + oK] = sv;
      float qr = bf2f(sv);
      nlds[row * 65 + oK] = qr * qr;
    }
  __syncthreads();
  if (tid < 64) {
    float ss = 0.f;
#pragma unroll 8
    for (int j = 0; j < 64; ++j) ss += nlds[tid * 65 + j];
#pragma unroll
    for (int m = 1; m <= 32; m <<= 1) ss = fmaxf(ss, __shfl_xor(ss, m, 64));
    if (tid == 0) atomicMax(&kmax2[b], __float_as_uint(ss));
  }
}

// ---------------------------------------------------------------------------
// Flash attention + residual.  LDS-staged K/V (global_load_lds, dbuf).
// wg = 4 waves = 64 q-rows x 128 cols; wave = 16 q-rows x 128 cols
// (QK/softmax duplication x2, was x4 -- halves QK MFMA + exp VALU).
// STATIC softmax shift (Cauchy-Schwarz) folded into QK C-init; no max, no
// cross-lane reduce, no branch in the loop.  Same staging/swizzles as R8/R10.
// ---------------------------------------------------------------------------
__global__ __launch_bounds__(256, 2)
void flash_kernel(const short* __restrict__ Q, const short* __restrict__ K,
                  const short* __restrict__ Vt, const float* __restrict__ src,
                  const float* __restrict__ gamma_p,
                  const float* __restrict__ qnorm2, const unsigned* __restrict__ kmax2,
                  float* __restrict__ out)
{
  // arena: K dbuf 2x8KB at 0; V dbuf 2x16KB at 16384; epilogue reuse.
  __shared__ alignas(16) char arena[49152];

  const int tid = threadIdx.x;
  const int wv = tid >> 6, l = tid & 63;
  const int l15 = l & 15, l4 = l >> 4;

  // id -> (b, qt, z); batch pinned to an XCD pair for L2 locality
  const int id = blockIdx.x;
  const int x8 = id & 7;
  const int b  = x8 >> 1;
  const int widx = ((id >> 3) << 1) | (x8 & 1);   // 0..127
  const int qt = widx >> 1, z = widx & 1;
  const int i0 = qt * 64;
  const int cbase = z * 128;
  const int rowbase = i0 + wv * 16;               // wave's 16 query rows

  const short* Qb = Q + (size_t)b * NT * 64;
  const char*  Kb = (const char*)(K  + (size_t)b * NT * 64);
  const char*  Vb = (const char*)(Vt + (size_t)b * CF * NT);

  // Q fragments (B-operand: col=l15 -> query rowbase+l15, k=l4*8..)
  bf16x8 qf[2];
#pragma unroll
  for (int kk = 0; kk < 2; ++kk)
    qf[kk] = *(const bf16x8*)&Qb[(size_t)(rowbase + l15) * 64 + kk * 32 + l4 * 8];

  // static shift: C-init for QK = -M_i = -sqrt(qnorm2_i * kmax2)
  const float km2 = __uint_as_float(kmax2[b]);
  f32x4 c0;
  {
    float mneg = -sqrtf(qnorm2[(size_t)b * NT + rowbase + l15] * km2);
    c0[0] = mneg; c0[1] = mneg; c0[2] = mneg; c0[3] = mneg;
  }

  const int a32 = ((l ^ 32) << 2);                // bpermute byte index (epilogue)

  // reader per-lane byte offsets (loop-invariant)
  const int kperm = 8 * (l15 >> 2) + (l15 & 3);
  const int swzk = (l15 & 3) | (((l15 >> 2) & 1) << 2);
  const int swzv = (l15 & 3) | (((l15 >> 3) & 1) << 2);
  int baseK[2], baseV[2];
#pragma unroll
  for (int kk = 0; kk < 2; ++kk) {
    baseK[kk] = kperm * 128 + (((kk * 4 + l4) ^ swzk) << 4);
    baseV[kk] = l15 * 128 + (((kk * 4 + l4) ^ swzv) << 4);
  }

  // staging: 24 1KB chunks/tile (K 8, V 16), 6 per wave; linear LDS dest +
  // inverse-swizzled global source (swz = (row&3) | ((row>>3&1)<<2))
  const char* sptr[6]; int sinc[6], doff0[6], dadd[6];
#pragma unroll
  for (int i = 0; i < 6; ++i) {
    int c = wv * 6 + i;
    if (c < 8) {              // K chunk: rows 8c..8c+7 (128B rows)
      int r = c * 8 + (l >> 3);
      int sw = (r & 3) | (((r >> 3) & 1) << 2);
      sptr[i] = Kb + r * 128 + (((l & 7) ^ sw) << 4);
      sinc[i] = 8192;         // next 64 keys
      doff0[i] = c * 1024;
      dadd[i] = 8192;
    } else {                  // V chunk: channels 8(c-8)..+7 of wg's 128
      int vr = (c - 8) * 8 + (l >> 3);
      int sw = (vr & 3) | (((vr >> 3) & 1) << 2);
      sptr[i] = Vb + (size_t)(cbase + vr) * (NT * 2) + (((l & 7) ^ sw) << 4);
      sinc[i] = 128;          // next 64 keys
      doff0[i] = 16384 + (c - 8) * 1024;
      dadd[i] = 16384;
    }
  }

  // prologue: stage tile 0 into parity 0
#pragma unroll
  for (int i = 0; i < 6; ++i) {
    glds16(sptr[i], arena + doff0[i]);
    sptr[i] += sinc[i];
  }
  __syncthreads();

  f32x4 acc[8] = {};
  float lrow = 0.f;   // per-lane PARTIAL sum (own 16 key-slots)

  for (int jb = 0; jb < 64; ++jb) {
    const int cur = jb & 1;
    const char* Kc = arena + cur * 8192;
    const char* Vc = arena + 16384 + cur * 16384;

    // stage next tile (async; has the whole compute phase to land)
    if (jb < 63) {
      const int p = cur ^ 1;
#pragma unroll
      for (int i = 0; i < 6; ++i) {
        glds16(sptr[i], arena + doff0[i] + p * dadd[i]);
        sptr[i] += sinc[i];
      }
    }

    // K fragments (A-operand, permuted rows)
    bf16x8 kf[4][2];
#pragma unroll
    for (int nj = 0; nj < 4; ++nj) {
      const int ko = (nj >> 1) * 4096 + (nj & 1) * 512;
#pragma unroll
      for (int kk = 0; kk < 2; ++kk)
        kf[nj][kk] = *(const bf16x8*)(Kc + baseK[kk] + ko);
    }

    // S^T = K_perm @ Q^T - M  (static shift folded into C-init)
    f32x4 s[4];
    __builtin_amdgcn_s_setprio(1);
#pragma unroll
    for (int nj = 0; nj < 4; ++nj) {
      s[nj] = __builtin_amdgcn_mfma_f32_16x16x32_bf16(kf[nj][0], qf[0], c0, 0, 0, 0);
      s[nj] = __builtin_amdgcn_mfma_f32_16x16x32_bf16(kf[nj][1], qf[1], s[nj], 0, 0, 0);
    }
    __builtin_amdgcn_s_setprio(0);

    // V fragments (B-operand): wave reads all 128 wg-cols (16 per nv)
    bf16x8 vb[8][2];
#pragma unroll
    for (int nv = 0; nv < 8; ++nv)
#pragma unroll
      for (int kk = 0; kk < 2; ++kk)
        vb[nv][kk] = *(const bf16x8*)(Vc + baseV[kk] + nv * 2048);

    // softmax numerators: p = 2^s (s <= ~0 by the static bound); no reduce,
    // no branch.  Per-lane partial sum accumulates into lrow.
#pragma unroll
    for (int nj = 0; nj < 4; ++nj)
#pragma unroll
      for (int r = 0; r < 4; ++r)
        s[nj][r] = fexp2(s[nj][r]);

    lrow += ((s[0][0] + s[0][1]) + (s[0][2] + s[0][3]))
          + ((s[1][0] + s[1][1]) + (s[1][2] + s[1][3]))
          + ((s[2][0] + s[2][1]) + (s[2][2] + s[2][3]))
          + ((s[3][0] + s[3][1]) + (s[3][2] + s[3][3]));

    unsigned pk[4][2];
#pragma unroll
    for (int nj = 0; nj < 4; ++nj)
#pragma unroll
      for (int h = 0; h < 2; ++h)
        asm("v_cvt_pk_bf16_f32 %0, %1, %2"
            : "=v"(pk[nj][h]) : "v"(s[nj][2 * h]), "v"(s[nj][2 * h + 1]));
    bf16x8 pa[2];
#pragma unroll
    for (int kk = 0; kk < 2; ++kk) {
      union { unsigned u[4]; bf16x8 v; } u;
      u.u[0] = pk[2 * kk][0];     u.u[1] = pk[2 * kk][1];
      u.u[2] = pk[2 * kk + 1][0]; u.u[3] = pk[2 * kk + 1][1];
      pa[kk] = u.v;
    }

    // O += P @ V
    __builtin_amdgcn_s_setprio(1);
#pragma unroll
    for (int kk = 0; kk < 2; ++kk)
#pragma unroll
      for (int nv = 0; nv < 8; ++nv)
        acc[nv] = __builtin_amdgcn_mfma_f32_16x16x32_bf16(pa[kk], vb[nv][kk], acc[nv], 0, 0, 0);
    __builtin_amdgcn_s_setprio(0);

    __syncthreads();   // implicit vmcnt(0): next-tile stage landed; reads done
  }

  // ---- epilogue: reduce row sums ONCE, normalize, transpose, residual ----
  float* Obuf = (float*)(void*)arena + wv * (16 * 132);
  const float gm = gamma_p[0];
  const float* srcb = src + (size_t)b * CF * NT;
  float* outb = out + (size_t)b * CF * NT;

  float lf = lrow;
  lf += __int_as_float(__builtin_amdgcn_ds_swizzle(__float_as_int(lf), 0x401F));
  lf += __int_as_float(__builtin_amdgcn_ds_bpermute(a32, __float_as_int(lf)));
  float li[4];
#pragma unroll
  for (int r = 0; r < 4; ++r)
    li[r] = 1.0f / __shfl(lf, 4 * l4 + r, 64);
#pragma unroll
  for (int nv = 0; nv < 8; ++nv)
#pragma unroll
    for (int r = 0; r < 4; ++r)
      Obuf[(4 * l4 + r) * 132 + 16 * nv + l15] = acc[nv][r] * li[r];
  // same-wave LDS write->read; per-wave disjoint regions, no barrier needed
#pragma unroll 4
  for (int t = 0; t < 32; ++t) {
    int c = cbase + l4 + 4 * t;
    size_t off = (size_t)c * NT + rowbase + l15;
    float v = Obuf[l15 * 132 + l4 + 4 * t];
    outb[off] = gm * v + srcb[off];
  }
}

// ---------------------------------------------------------------------------
extern "C" void kernel_launch(void* const* d_in, const int* in_sizes, int n_in,
                              void* d_out, int out_size, void* d_ws, size_t ws_size,
                              hipStream_t stream) {
  const float* src    = (const float*)d_in[0];
  const float* ref    = (const float*)d_in[1];
  const float* w_src  = (const float*)d_in[2];
  const float* b_src  = (const float*)d_in[3];
  const float* w_ref  = (const float*)d_in[4];
  const float* b_ref  = (const float*)d_in[5];
  const float* w_gate = (const float*)d_in[6];
  const float* b_gate = (const float*)d_in[7];
  const float* gamma  = (const float*)d_in[8];
  float* out = (float*)d_out;

  const size_t qk_elems = (size_t)4 * NT * 64;
  const size_t v_elems  = (size_t)4 * CF * NT;
  const size_t base_bytes = (qk_elems * 2 + v_elems) * sizeof(short);
  if (ws_size < base_bytes + 4 * NT * sizeof(float) + 4 * sizeof(unsigned)) return;
  short* Qw = (short*)d_ws;
  short* Kw = Qw + qk_elems;
  short* Vw = Kw + qk_elems;
  float* qnormp = (float*)(Vw + v_elems);
  unsigned* kmaxp = (unsigned*)(qnormp + 4 * NT);

  hipMemsetAsync(kmaxp, 0, 4 * sizeof(unsigned), stream);

  dim3 blk(256);
  dim3 gp(NT / 64, 4);
  // fold energy scale (1/16) AND log2(e) into Q so scores are log2-domain
  proj_src_kernel<<<gp, blk, 0, stream>>>(src, w_src, b_src, Qw,
                                          0.0625f * 1.44269504f, qnormp);
  proj_ref_kernel<<<gp, blk, 0, stream>>>(ref, w_ref, b_ref, w_gate, b_gate,
                                          Kw, Vw, kmaxp);

  flash_kernel<<<dim3(512), blk, 0, stream>>>(Qw, Kw, Vw, src, gamma, qnormp, kmaxp, out);
}

// Round 12
// 95.938 us; speedup vs baseline: 2.5990x; 1.0664x over previous
//
#include <hip/hip_runtime.h>
#include <hip/hip_bf16.h>

#define NT 4096      // H*W
#define CF 256       // feature channels
// CQK = 64

typedef __attribute__((ext_vector_type(8))) short bf16x8;
typedef __attribute__((ext_vector_type(4))) float f32x4;
typedef __attribute__((ext_vector_type(4))) short s16x4;

__device__ __forceinline__ short f2bf(float f) {
  union { float f; unsigned u; } v; v.f = f;
  unsigned r = v.u + 0x7FFFu + ((v.u >> 16) & 1u);   // RTNE
  return (short)(r >> 16);
}
__device__ __forceinline__ float bf2f(short s) {
  union { unsigned u; float f; } w; w.u = ((unsigned)(unsigned short)s) << 16;
  return w.f;
}

// async global->LDS, 16B per lane; LDS dest = wave-uniform base + lane*16
__device__ __forceinline__ void glds16(const void* g, void* l) {
  __builtin_amdgcn_global_load_lds(
      (const __attribute__((address_space(1))) void*)g,
      (__attribute__((address_space(3))) void*)l, 16, 0, 0);
}

// bare hardware exp2 (log2-domain scores shifted to <= ~0; finite args)
__device__ __forceinline__ float fexp2(float x) {
  float r;
  asm("v_exp_f32 %0, %1" : "=v"(r) : "v"(x));
  return r;
}

// ---------------------------------------------------------------------------
// Q projection + per-row squared norm (for the static softmax bound).
// ---------------------------------------------------------------------------
__global__ __launch_bounds__(256, 2)
void proj_src_kernel(const float* __restrict__ X, const float* __restrict__ W,
                     const float* __restrict__ Bv, short* __restrict__ Y,
                     float scale, float* __restrict__ qnorm2)
{
  __shared__ alignas(16) short Xlds[64 * 256];   // 32KB; reused as norm scratch
  const int tid = threadIdx.x;
  const int wv = tid >> 6, l = tid & 63;
  const int l15 = l & 15, l4 = l >> 4;
  const int i0 = blockIdx.x * 64;
  const int b  = blockIdx.y;
  const float* Xb = X + (size_t)b * CF * NT;

#pragma unroll
  for (int it = 0; it < 16; ++it) {
    int c0 = it * 16 + wv * 4;
    float x0 = Xb[(size_t)(c0 + 0) * NT + i0 + l];
    float x1 = Xb[(size_t)(c0 + 1) * NT + i0 + l];
    float x2 = Xb[(size_t)(c0 + 2) * NT + i0 + l];
    float x3 = Xb[(size_t)(c0 + 3) * NT + i0 + l];
    s16x4 pk; pk[0] = f2bf(x0); pk[1] = f2bf(x1); pk[2] = f2bf(x2); pk[3] = f2bf(x3);
    int phys = (l * 512 + c0 * 2) ^ ((l & 31) << 4);
    *(s16x4*)((char*)Xlds + phys) = pk;
  }
  __syncthreads();

  f32x4 acc[4] = {};
  const int o = wv * 16 + l15;

#pragma unroll
  for (int kk = 0; kk < 8; ++kk) {
    bf16x8 a[4];
#pragma unroll
    for (int mi = 0; mi < 4; ++mi) {
      int i = 16 * mi + l15;
      int phys = (i * 512 + kk * 64 + l4 * 16) ^ ((i & 31) << 4);
      a[mi] = *(const bf16x8*)((const char*)Xlds + phys);
    }
    const float* wp = W + (size_t)o * CF + kk * 32 + l4 * 8;
    bf16x8 wf;
#pragma unroll
    for (int t = 0; t < 8; ++t) wf[t] = f2bf(wp[t]);
#pragma unroll
    for (int mi = 0; mi < 4; ++mi)
      acc[mi] = __builtin_amdgcn_mfma_f32_16x16x32_bf16(a[mi], wf, acc[mi], 0, 0, 0);
  }

  __syncthreads();                         // all waves done reading Xlds
  float* nlds = (float*)(void*)Xlds;       // [64][65] padded sq matrix
  const float bv = Bv[o];
#pragma unroll
  for (int mi = 0; mi < 4; ++mi)
#pragma unroll
    for (int r = 0; r < 4; ++r) {
      float val = (acc[mi][r] + bv) * scale;
      short sv = f2bf(val);
      int row = 16 * mi + l4 * 4 + r;
      Y[((size_t)b * NT + i0 + row) * 64 + o] = sv;
      float qr = bf2f(sv);
      nlds[row * 65 + o] = qr * qr;
    }
  __syncthreads();
  if (tid < 64) {
    float ss = 0.f;
#pragma unroll 8
    for (int j = 0; j < 64; ++j) ss += nlds[tid * 65 + j];
    qnorm2[(size_t)b * NT + i0 + tid] = ss;
  }
}

// ---------------------------------------------------------------------------
// Fused ref projections: K (B,NT,64) and Vt (B,256,NT) from ONE staging of
// ref, plus kmax2[b] = max_row |k_row|^2 (one atomicMax per wg).
// ---------------------------------------------------------------------------
__global__ __launch_bounds__(256, 2)
void proj_ref_kernel(const float* __restrict__ X,
                     const float* __restrict__ Wk, const float* __restrict__ Bk,
                     const float* __restrict__ Wv, const float* __restrict__ Bvv,
                     short* __restrict__ K, short* __restrict__ Vt,
                     unsigned* __restrict__ kmax2)
{
  __shared__ alignas(16) short Xlds[64 * 256];
  const int tid = threadIdx.x;
  const int wv = tid >> 6, l = tid & 63;
  const int l15 = l & 15, l4 = l >> 4;
  const int i0 = blockIdx.x * 64;
  const int b  = blockIdx.y;
  const float* Xb = X + (size_t)b * CF * NT;

#pragma unroll
  for (int it = 0; it < 16; ++it) {
    int c0 = it * 16 + wv * 4;
    float x0 = Xb[(size_t)(c0 + 0) * NT + i0 + l];
    float x1 = Xb[(size_t)(c0 + 1) * NT + i0 + l];
    float x2 = Xb[(size_t)(c0 + 2) * NT + i0 + l];
    float x3 = Xb[(size_t)(c0 + 3) * NT + i0 + l];
    s16x4 pk; pk[0] = f2bf(x0); pk[1] = f2bf(x1); pk[2] = f2bf(x2); pk[3] = f2bf(x3);
    int phys = (l * 512 + c0 * 2) ^ ((l & 31) << 4);
    *(s16x4*)((char*)Xlds + phys) = pk;
  }
  __syncthreads();

  f32x4 accK[4] = {};
  f32x4 accV[4][4] = {};
  const int oK = wv * 16 + l15;

#pragma unroll
  for (int kk = 0; kk < 8; ++kk) {
    bf16x8 a[4];
#pragma unroll
    for (int mi = 0; mi < 4; ++mi) {
      int i = 16 * mi + l15;
      int phys = (i * 512 + kk * 64 + l4 * 16) ^ ((i & 31) << 4);
      a[mi] = *(const bf16x8*)((const char*)Xlds + phys);
    }
    {
      const float* wp = Wk + (size_t)oK * CF + kk * 32 + l4 * 8;
      bf16x8 wf;
#pragma unroll
      for (int t = 0; t < 8; ++t) wf[t] = f2bf(wp[t]);
#pragma unroll
      for (int mi = 0; mi < 4; ++mi)
        accK[mi] = __builtin_amdgcn_mfma_f32_16x16x32_bf16(a[mi], wf, accK[mi], 0, 0, 0);
    }
#pragma unroll
    for (int no = 0; no < 4; ++no) {
      int oV = wv * 64 + 16 * no + l15;
      const float* wp = Wv + (size_t)oV * CF + kk * 32 + l4 * 8;
      bf16x8 wf;
#pragma unroll
      for (int t = 0; t < 8; ++t) wf[t] = f2bf(wp[t]);
#pragma unroll
      for (int mi = 0; mi < 4; ++mi)
        accV[mi][no] = __builtin_amdgcn_mfma_f32_16x16x32_bf16(a[mi], wf, accV[mi][no], 0, 0, 0);
    }
  }

#pragma unroll
  for (int no = 0; no < 4; ++no) {
    int oV = wv * 64 + 16 * no + l15;
    float bv = Bvv[oV];
#pragma unroll
    for (int mi = 0; mi < 4; ++mi) {
      s16x4 pk;
#pragma unroll
      for (int r = 0; r < 4; ++r) pk[r] = f2bf(accV[mi][no][r] + bv);
      *(s16x4*)&Vt[((size_t)b * CF + oV) * NT + i0 + 16 * mi + l4 * 4] = pk;
    }
  }

  __syncthreads();                         // all waves done reading Xlds
  float* nlds = (float*)(void*)Xlds;       // [64][65]
  const float bk = Bk[oK];
#pragma unroll
  for (int mi = 0; mi < 4; ++mi)
#pragma unroll
    for (int r = 0; r < 4; ++r) {
      float val = accK[mi][r] + bk;
      short sv = f2bf(val);
      int row = 16 * mi + l4 * 4 + r;
      K[((size_t)b * NT + i0 + row) * 64 + oK] = sv;
      float qr = bf2f(sv);
      nlds[row * 65 + oK] = qr * qr;
    }
  __syncthreads();
  if (tid < 64) {
    float ss = 0.f;
#pragma unroll 8
    for (int j = 0; j < 64; ++j) ss += nlds[tid * 65 + j];
#pragma unroll
    for (int m = 1; m <= 32; m <<= 1) ss = fmaxf(ss, __shfl_xor(ss, m, 64));
    if (tid == 0) atomicMax(&kmax2[b], __float_as_uint(ss));
  }
}

// ---------------------------------------------------------------------------
// Flash attention + residual.  LDS-staged K/V (global_load_lds, dbuf).
// wg = 8 waves (512 thr) = 128 q-rows x 128 cols; wave = 16 q-rows x 128 cols
// (per-wave code identical to R11; one wg per CU stages K/V ONCE per tile,
// halving LDS staging traffic vs two 4-wave wgs).
// STATIC softmax shift (Cauchy-Schwarz) folded into QK C-init; no max, no
// cross-lane reduce, no branch in the loop.
// Arena 48KB: K dbuf 2x8KB at 0; V dbuf 2x16KB at 16384; epilogue reuse
// (two 64-col halves so 8 waves fit).
// ---------------------------------------------------------------------------
__global__ __launch_bounds__(512, 2)
void flash_kernel(const short* __restrict__ Q, const short* __restrict__ K,
                  const short* __restrict__ Vt, const float* __restrict__ src,
                  const float* __restrict__ gamma_p,
                  const float* __restrict__ qnorm2, const unsigned* __restrict__ kmax2,
                  float* __restrict__ out)
{
  __shared__ alignas(16) char arena[49152];

  const int tid = threadIdx.x;
  const int wv = tid >> 6, l = tid & 63;     // wv = 0..7
  const int l15 = l & 15, l4 = l >> 4;

  // id -> (b, qt, z); batch pinned to an XCD pair for L2 locality
  const int id = blockIdx.x;                 // 0..255
  const int x8 = id & 7;
  const int b  = x8 >> 1;
  const int widx = ((id >> 3) << 1) | (x8 & 1);   // 0..63
  const int qt = widx >> 1, z = widx & 1;
  const int i0 = qt * 128;
  const int cbase = z * 128;
  const int rowbase = i0 + wv * 16;               // wave's 16 query rows

  const short* Qb = Q + (size_t)b * NT * 64;
  const char*  Kb = (const char*)(K  + (size_t)b * NT * 64);
  const char*  Vb = (const char*)(Vt + (size_t)b * CF * NT);

  // Q fragments (B-operand: col=l15 -> query rowbase+l15, k=l4*8..)
  bf16x8 qf[2];
#pragma unroll
  for (int kk = 0; kk < 2; ++kk)
    qf[kk] = *(const bf16x8*)&Qb[(size_t)(rowbase + l15) * 64 + kk * 32 + l4 * 8];

  // static shift: C-init for QK = -M_i = -sqrt(qnorm2_i * kmax2)
  const float km2 = __uint_as_float(kmax2[b]);
  f32x4 c0;
  {
    float mneg = -sqrtf(qnorm2[(size_t)b * NT + rowbase + l15] * km2);
    c0[0] = mneg; c0[1] = mneg; c0[2] = mneg; c0[3] = mneg;
  }

  const int a32 = ((l ^ 32) << 2);                // bpermute byte index (epilogue)

  // reader per-lane byte offsets (loop-invariant)
  const int kperm = 8 * (l15 >> 2) + (l15 & 3);
  const int swzk = (l15 & 3) | (((l15 >> 2) & 1) << 2);
  const int swzv = (l15 & 3) | (((l15 >> 3) & 1) << 2);
  int baseK[2], baseV[2];
#pragma unroll
  for (int kk = 0; kk < 2; ++kk) {
    baseK[kk] = kperm * 128 + (((kk * 4 + l4) ^ swzk) << 4);
    baseV[kk] = l15 * 128 + (((kk * 4 + l4) ^ swzv) << 4);
  }

  // staging: 24 1KB chunks/tile (K 8, V 16), 3 per wave; linear LDS dest +
  // inverse-swizzled global source (swz = (row&3) | ((row>>3&1)<<2))
  const char* sptr[3]; int sinc[3], doff0[3], dadd[3];
#pragma unroll
  for (int i = 0; i < 3; ++i) {
    int c = wv * 3 + i;
    if (c < 8) {              // K chunk: rows 8c..8c+7 (128B rows)
      int r = c * 8 + (l >> 3);
      int sw = (r & 3) | (((r >> 3) & 1) << 2);
      sptr[i] = Kb + r * 128 + (((l & 7) ^ sw) << 4);
      sinc[i] = 8192;         // next 64 keys
      doff0[i] = c * 1024;
      dadd[i] = 8192;
    } else {                  // V chunk: channels 8(c-8)..+7 of wg's 128
      int vr = (c - 8) * 8 + (l >> 3);
      int sw = (vr & 3) | (((vr >> 3) & 1) << 2);
      sptr[i] = Vb + (size_t)(cbase + vr) * (NT * 2) + (((l & 7) ^ sw) << 4);
      sinc[i] = 128;          // next 64 keys
      doff0[i] = 16384 + (c - 8) * 1024;
      dadd[i] = 16384;
    }
  }

  // prologue: stage tile 0 into parity 0
#pragma unroll
  for (int i = 0; i < 3; ++i) {
    glds16(sptr[i], arena + doff0[i]);
    sptr[i] += sinc[i];
  }
  __syncthreads();

  f32x4 acc[8] = {};
  float lrow = 0.f;   // per-lane PARTIAL sum (own 16 key-slots)

  for (int jb = 0; jb < 64; ++jb) {
    const int cur = jb & 1;
    const char* Kc = arena + cur * 8192;
    const char* Vc = arena + 16384 + cur * 16384;

    // stage next tile (async; has the whole compute phase to land)
    if (jb < 63) {
      const int p = cur ^ 1;
#pragma unroll
      for (int i = 0; i < 3; ++i) {
        glds16(sptr[i], arena + doff0[i] + p * dadd[i]);
        sptr[i] += sinc[i];
      }
    }

    // K fragments (A-operand, permuted rows)
    bf16x8 kf[4][2];
#pragma unroll
    for (int nj = 0; nj < 4; ++nj) {
      const int ko = (nj >> 1) * 4096 + (nj & 1) * 512;
#pragma unroll
      for (int kk = 0; kk < 2; ++kk)
        kf[nj][kk] = *(const bf16x8*)(Kc + baseK[kk] + ko);
    }

    // S^T = K_perm @ Q^T - M  (static shift folded into C-init)
    f32x4 s[4];
    __builtin_amdgcn_s_setprio(1);
#pragma unroll
    for (int nj = 0; nj < 4; ++nj) {
      s[nj] = __builtin_amdgcn_mfma_f32_16x16x32_bf16(kf[nj][0], qf[0], c0, 0, 0, 0);
      s[nj] = __builtin_amdgcn_mfma_f32_16x16x32_bf16(kf[nj][1], qf[1], s[nj], 0, 0, 0);
    }
    __builtin_amdgcn_s_setprio(0);

    // V fragments (B-operand): wave reads all 128 wg-cols (16 per nv)
    bf16x8 vb[8][2];
#pragma unroll
    for (int nv = 0; nv < 8; ++nv)
#pragma unroll
      for (int kk = 0; kk < 2; ++kk)
        vb[nv][kk] = *(const bf16x8*)(Vc + baseV[kk] + nv * 2048);

    // softmax numerators: p = 2^s (s <= ~0 by the static bound); no reduce,
    // no branch.  Per-lane partial sum accumulates into lrow.
#pragma unroll
    for (int nj = 0; nj < 4; ++nj)
#pragma unroll
      for (int r = 0; r < 4; ++r)
        s[nj][r] = fexp2(s[nj][r]);

    lrow += ((s[0][0] + s[0][1]) + (s[0][2] + s[0][3]))
          + ((s[1][0] + s[1][1]) + (s[1][2] + s[1][3]))
          + ((s[2][0] + s[2][1]) + (s[2][2] + s[2][3]))
          + ((s[3][0] + s[3][1]) + (s[3][2] + s[3][3]));

    unsigned pk[4][2];
#pragma unroll
    for (int nj = 0; nj < 4; ++nj)
#pragma unroll
      for (int h = 0; h < 2; ++h)
        asm("v_cvt_pk_bf16_f32 %0, %1, %2"
            : "=v"(pk[nj][h]) : "v"(s[nj][2 * h]), "v"(s[nj][2 * h + 1]));
    bf16x8 pa[2];
#pragma unroll
    for (int kk = 0; kk < 2; ++kk) {
      union { unsigned u[4]; bf16x8 v; } u;
      u.u[0] = pk[2 * kk][0];     u.u[1] = pk[2 * kk][1];
      u.u[2] = pk[2 * kk + 1][0]; u.u[3] = pk[2 * kk + 1][1];
      pa[kk] = u.v;
    }

    // O += P @ V
    __builtin_amdgcn_s_setprio(1);
#pragma unroll
    for (int kk = 0; kk < 2; ++kk)
#pragma unroll
      for (int nv = 0; nv < 8; ++nv)
        acc[nv] = __builtin_amdgcn_mfma_f32_16x16x32_bf16(pa[kk], vb[nv][kk], acc[nv], 0, 0, 0);
    __builtin_amdgcn_s_setprio(0);

    __syncthreads();   // implicit vmcnt(0): next-tile stage landed; reads done
  }

  // ---- epilogue: reduce row sums ONCE, normalize, transpose, residual ----
  // two 64-col halves so 8 waves' Obuf (16x68 f32 each) fits the arena;
  // DS ops are in-order per wave, so no barrier between halves.
  float* Obuf = (float*)(void*)arena + wv * (16 * 68);
  const float gm = gamma_p[0];
  const float* srcb = src + (size_t)b * CF * NT;
  float* outb = out + (size_t)b * CF * NT;

  float lf = lrow;
  lf += __int_as_float(__builtin_amdgcn_ds_swizzle(__float_as_int(lf), 0x401F));
  lf += __int_as_float(__builtin_amdgcn_ds_bpermute(a32, __float_as_int(lf)));
  float li[4];
#pragma unroll
  for (int r = 0; r < 4; ++r)
    li[r] = 1.0f / __shfl(lf, 4 * l4 + r, 64);

#pragma unroll
  for (int h = 0; h < 2; ++h) {
#pragma unroll
    for (int nv = 0; nv < 4; ++nv)
#pragma unroll
      for (int r = 0; r < 4; ++r)
        Obuf[(4 * l4 + r) * 68 + 16 * nv + l15] = acc[h * 4 + nv][r] * li[r];
#pragma unroll 4
    for (int t = 0; t < 16; ++t) {
      int c = cbase + h * 64 + l4 + 4 * t;
      size_t off = (size_t)c * NT + rowbase + l15;
      float v = Obuf[l15 * 68 + l4 + 4 * t];
      outb[off] = gm * v + srcb[off];
    }
  }
}

// ---------------------------------------------------------------------------
extern "C" void kernel_launch(void* const* d_in, const int* in_sizes, int n_in,
                              void* d_out, int out_size, void* d_ws, size_t ws_size,
                              hipStream_t stream) {
  const float* src    = (const float*)d_in[0];
  const float* ref    = (const float*)d_in[1];
  const float* w_src  = (const float*)d_in[2];
  const float* b_src  = (const float*)d_in[3];
  const float* w_ref  = (const float*)d_in[4];
  const float* b_ref  = (const float*)d_in[5];
  const float* w_gate = (const float*)d_in[6];
  const float* b_gate = (const float*)d_in[7];
  const float* gamma  = (const float*)d_in[8];
  float* out = (float*)d_out;

  const size_t qk_elems = (size_t)4 * NT * 64;
  const size_t v_elems  = (size_t)4 * CF * NT;
  const size_t base_bytes = (qk_elems * 2 + v_elems) * sizeof(short);
  if (ws_size < base_bytes + 4 * NT * sizeof(float) + 4 * sizeof(unsigned)) return;
  short* Qw = (short*)d_ws;
  short* Kw = Qw + qk_elems;
  short* Vw = Kw + qk_elems;
  float* qnormp = (float*)(Vw + v_elems);
  unsigned* kmaxp = (unsigned*)(qnormp + 4 * NT);

  hipMemsetAsync(kmaxp, 0, 4 * sizeof(unsigned), stream);

  dim3 blk(256);
  dim3 gp(NT / 64, 4);
  // fold energy scale (1/16) AND log2(e) into Q so scores are log2-domain
  proj_src_kernel<<<gp, blk, 0, stream>>>(src, w_src, b_src, Qw,
                                          0.0625f * 1.44269504f, qnormp);
  proj_ref_kernel<<<gp, blk, 0, stream>>>(ref, w_ref, b_ref, w_gate, b_gate,
                                          Kw, Vw, kmaxp);

  flash_kernel<<<dim3(256), dim3(512), 0, stream>>>(Qw, Kw, Vw, src, gamma, qnormp, kmaxp, out);
}